// Round 1
// baseline (401.907 us; speedup 1.0000x reference)
//
#include <hip/hip_runtime.h>
#include <cstdint>
#include <cstddef>

// ReservoirRNNCell: B=16, I=1024, H=2048
// out[b,o] = tanh( x_t[b,:]·W_ih[o,:] + b_ih[o] + (Σ_h E[o,h]·r(u[b,o,h])·h_prev[b,h]) / (Σ_h E[o,h]·r(u[b,o,h])) )
// where E[o,h] = exp((W_hh*mask)/tau), r(u) = 1/log2(u)  (constant -ln2 scale cancels in ratio)

#define LOG2E 1.4426950408889634f

__global__ __launch_bounds__(256) void precompute_E_kernel(
    const float* __restrict__ Whh, const float* __restrict__ mask,
    const float* __restrict__ temp, float* __restrict__ E, int n4) {
  float tau = fmaxf(temp[0], 1e-3f);
  float sc = LOG2E / tau;
  int stride = gridDim.x * blockDim.x;
  for (int i = blockIdx.x * blockDim.x + threadIdx.x; i < n4; i += stride) {
    float4 w = ((const float4*)Whh)[i];
    float4 m = ((const float4*)mask)[i];
    float4 e;
    e.x = __builtin_amdgcn_exp2f(w.x * m.x * sc);
    e.y = __builtin_amdgcn_exp2f(w.y * m.y * sc);
    e.z = __builtin_amdgcn_exp2f(w.z * m.z * sc);
    e.w = __builtin_amdgcn_exp2f(w.w * m.w * sc);
    ((float4*)E)[i] = e;
  }
}

template <bool PRE>
__global__ __launch_bounds__(256) void rnn_main_kernel(
    const float* __restrict__ x,      // [16,1024]
    const float* __restrict__ hprev,  // [16,2048]
    const float* __restrict__ Wih,    // [2048,1024]
    const float* __restrict__ bih,    // [2048]
    const float* __restrict__ Whh,    // [2048,2048]
    const float* __restrict__ temp,   // [1]
    const float* __restrict__ mask,   // [2048,2048]
    const float* __restrict__ u,      // [16,2048,2048]
    const float* __restrict__ E,      // [2048,2048] (PRE) or unused
    float* __restrict__ out)          // [16,2048]
{
  const int lane = threadIdx.x & 63;
  const int wid  = threadIdx.x >> 6;
  const int row  = (blockIdx.x << 2) + wid;   // 0..32767, row = b*2048 + o
  const int b = row >> 11;
  const int o = row & 2047;

  const float4* up = (const float4*)(u + ((size_t)row << 11));
  const float4* hp = (const float4*)(hprev + ((size_t)b << 11));

  const float4* ep = nullptr;
  const float4* wp = nullptr;
  const float4* mp = nullptr;
  float sc = 0.f;
  if (PRE) {
    ep = (const float4*)(E + ((size_t)o << 11));
  } else {
    wp = (const float4*)(Whh + ((size_t)o << 11));
    mp = (const float4*)(mask + ((size_t)o << 11));
    float tau = fmaxf(temp[0], 1e-3f);
    sc = LOG2E / tau;
  }

  float s = 0.f, wsum = 0.f;
#pragma unroll
  for (int it = 0; it < 8; ++it) {
    int idx = (it << 6) + lane;   // 8*64*4 = 2048 floats per row
    float4 uu = up[idx];
    float4 hh = hp[idx];
    float4 ee;
    if (PRE) {
      ee = ep[idx];
    } else {
      float4 w = wp[idx];
      float4 m = mp[idx];
      ee.x = __builtin_amdgcn_exp2f(w.x * m.x * sc);
      ee.y = __builtin_amdgcn_exp2f(w.y * m.y * sc);
      ee.z = __builtin_amdgcn_exp2f(w.z * m.z * sc);
      ee.w = __builtin_amdgcn_exp2f(w.w * m.w * sc);
    }
    // weight (scaled by -ln2, cancels in wsum/s):
    float w0 = ee.x * __builtin_amdgcn_rcpf(__builtin_amdgcn_logf(uu.x));
    float w1 = ee.y * __builtin_amdgcn_rcpf(__builtin_amdgcn_logf(uu.y));
    float w2 = ee.z * __builtin_amdgcn_rcpf(__builtin_amdgcn_logf(uu.z));
    float w3 = ee.w * __builtin_amdgcn_rcpf(__builtin_amdgcn_logf(uu.w));
    s += w0; wsum = fmaf(w0, hh.x, wsum);
    s += w1; wsum = fmaf(w1, hh.y, wsum);
    s += w2; wsum = fmaf(w2, hh.z, wsum);
    s += w3; wsum = fmaf(w3, hh.w, wsum);
  }

  // fused input_contrib: dot(x[b,:], Wih[o,:]) over I=1024
  const float4* xp  = (const float4*)(x + ((size_t)b << 10));
  const float4* wip = (const float4*)(Wih + ((size_t)o << 10));
  float ic = 0.f;
#pragma unroll
  for (int it = 0; it < 4; ++it) {
    int idx = (it << 6) + lane;   // 4*64*4 = 1024 floats
    float4 xx = xp[idx];
    float4 ww = wip[idx];
    ic = fmaf(xx.x, ww.x, ic);
    ic = fmaf(xx.y, ww.y, ic);
    ic = fmaf(xx.z, ww.z, ic);
    ic = fmaf(xx.w, ww.w, ic);
  }

  // wave-wide reductions (64 lanes)
#pragma unroll
  for (int off = 32; off > 0; off >>= 1) {
    s    += __shfl_xor(s, off, 64);
    wsum += __shfl_xor(wsum, off, 64);
    ic   += __shfl_xor(ic, off, 64);
  }

  if (lane == 0) {
    float contrib = wsum / s;
    out[row] = tanhf(ic + bih[o] + contrib);
  }
}

extern "C" void kernel_launch(void* const* d_in, const int* in_sizes, int n_in,
                              void* d_out, int out_size, void* d_ws, size_t ws_size,
                              hipStream_t stream) {
  const float* x     = (const float*)d_in[0];
  const float* hprev = (const float*)d_in[1];
  const float* Wih   = (const float*)d_in[2];
  const float* bih   = (const float*)d_in[3];
  const float* Whh   = (const float*)d_in[4];
  const float* temp  = (const float*)d_in[5];
  const float* mask  = (const float*)d_in[6];
  const float* u     = (const float*)d_in[7];
  float* out = (float*)d_out;

  const size_t EBYTES = (size_t)2048 * 2048 * sizeof(float);
  if (ws_size >= EBYTES) {
    float* E = (float*)d_ws;
    precompute_E_kernel<<<2048, 256, 0, stream>>>(Whh, mask, temp, E, 2048 * 2048 / 4);
    rnn_main_kernel<true><<<8192, 256, 0, stream>>>(x, hprev, Wih, bih, Whh, temp, mask, u, E, out);
  } else {
    rnn_main_kernel<false><<<8192, 256, 0, stream>>>(x, hprev, Wih, bih, Whh, temp, mask, u, nullptr, out);
  }
}

// Round 2
// 401.377 us; speedup vs baseline: 1.0013x; 1.0013x over previous
//
#include <hip/hip_runtime.h>
#include <cstdint>
#include <cstddef>

// ReservoirRNNCell: B=16, I=1024, H=2048
// out[b,o] = tanh( x[b,:]·Wih[o,:] + bih[o] + wsum/s ), where per (b,o):
//   s    = Σ_h E[o,h] * r(u[b,o,h])
//   wsum = Σ_h E[o,h] * r(u[b,o,h]) * hprev[b,h]
//   E[o,h] = exp((Whh[o,h]*mask[o,h])/tau),  r(u) = 1/log2(u)
// (softmax(l+g) weights: exp(l)*(-1/ln u); the -ln2 constant from using log2
//  cancels in the wsum/s ratio, as does the sign.)
//
// One block per output column o (1024 thr = 16 waves, wave w = batch b).
// E[o,:] is computed ONCE per block into LDS -> Whh/mask read exactly once
// chip-wide; u streamed once; everything else L1/L2-resident.

#define LOG2E 1.4426950408889634f

__global__ __launch_bounds__(1024) void rnn_fused_kernel(
    const float* __restrict__ x,      // [16,1024]
    const float* __restrict__ hprev,  // [16,2048]
    const float* __restrict__ Wih,    // [2048,1024]
    const float* __restrict__ bih,    // [2048]
    const float* __restrict__ Whh,    // [2048,2048]
    const float* __restrict__ temp,   // [1]
    const float* __restrict__ mask,   // [2048,2048]
    const float* __restrict__ u,      // [16,2048,2048]
    float* __restrict__ out)          // [16,2048]
{
  __shared__ float e_row[2048];

  const int o    = blockIdx.x;        // 0..2047
  const int tid  = threadIdx.x;       // 0..1023
  const int lane = tid & 63;
  const int b    = tid >> 6;          // wave id = batch index 0..15

  // ---- stage E[o,:] into LDS (each thread does 2 elements) ----
  {
    const float tau = fmaxf(temp[0], 1e-3f);
    const float sc  = LOG2E / tau;
    const float2* wp = (const float2*)(Whh  + ((size_t)o << 11));
    const float2* mp = (const float2*)(mask + ((size_t)o << 11));
    float2 ww = wp[tid];
    float2 mm = mp[tid];
    float2 ee;
    ee.x = __builtin_amdgcn_exp2f(ww.x * mm.x * sc);
    ee.y = __builtin_amdgcn_exp2f(ww.y * mm.y * sc);
    ((float2*)e_row)[tid] = ee;
  }
  __syncthreads();

  // ---- per-wave: stream u[b,o,:] (8 KB contiguous), accumulate s & wsum ----
  const float4* up  = (const float4*)(u + ((size_t)((b << 11) + o) << 11));
  const float4* hp  = (const float4*)(hprev + ((size_t)b << 11));
  const float4* ep4 = (const float4*)e_row;

  float s = 0.f, wsum = 0.f;
#pragma unroll
  for (int it = 0; it < 8; ++it) {
    int idx = (it << 6) + lane;       // 8 iters * 64 lanes * 4 floats = 2048
    float4 uu = up[idx];
    float4 hh = hp[idx];
    float4 ee = ep4[idx];             // ds_read_b128, contiguous: conflict-free
    float w0 = ee.x * __builtin_amdgcn_rcpf(__builtin_amdgcn_logf(uu.x));
    float w1 = ee.y * __builtin_amdgcn_rcpf(__builtin_amdgcn_logf(uu.y));
    float w2 = ee.z * __builtin_amdgcn_rcpf(__builtin_amdgcn_logf(uu.z));
    float w3 = ee.w * __builtin_amdgcn_rcpf(__builtin_amdgcn_logf(uu.w));
    s += w0; wsum = fmaf(w0, hh.x, wsum);
    s += w1; wsum = fmaf(w1, hh.y, wsum);
    s += w2; wsum = fmaf(w2, hh.z, wsum);
    s += w3; wsum = fmaf(w3, hh.w, wsum);
  }

  // ---- fused input_contrib: dot(x[b,:], Wih[o,:]) over I=1024 ----
  const float4* xp  = (const float4*)(x   + ((size_t)b << 10));
  const float4* wip = (const float4*)(Wih + ((size_t)o << 10));
  float ic = 0.f;
#pragma unroll
  for (int it = 0; it < 4; ++it) {
    int idx = (it << 6) + lane;       // 4*64*4 = 1024 floats
    float4 xx = xp[idx];
    float4 ww = wip[idx];
    ic = fmaf(xx.x, ww.x, ic);
    ic = fmaf(xx.y, ww.y, ic);
    ic = fmaf(xx.z, ww.z, ic);
    ic = fmaf(xx.w, ww.w, ic);
  }

  // ---- wave-wide reduction (64 lanes) ----
#pragma unroll
  for (int off = 32; off > 0; off >>= 1) {
    s    += __shfl_xor(s,    off, 64);
    wsum += __shfl_xor(wsum, off, 64);
    ic   += __shfl_xor(ic,   off, 64);
  }

  if (lane == 0) {
    out[(b << 11) + o] = tanhf(ic + bih[o] + wsum / s);
  }
}

extern "C" void kernel_launch(void* const* d_in, const int* in_sizes, int n_in,
                              void* d_out, int out_size, void* d_ws, size_t ws_size,
                              hipStream_t stream) {
  const float* x     = (const float*)d_in[0];
  const float* hprev = (const float*)d_in[1];
  const float* Wih   = (const float*)d_in[2];
  const float* bih   = (const float*)d_in[3];
  const float* Whh   = (const float*)d_in[4];
  const float* temp  = (const float*)d_in[5];
  const float* mask  = (const float*)d_in[6];
  const float* u     = (const float*)d_in[7];
  float* out = (float*)d_out;

  rnn_fused_kernel<<<2048, 1024, 0, stream>>>(x, hprev, Wih, bih, Whh, temp,
                                              mask, u, out);
}